// Round 1
// baseline (1224.632 us; speedup 1.0000x reference)
//
#include <hip/hip_runtime.h>

#define S_LEN 2048
#define HDIM  512
#define KSZ   64
#define S_T   128
// 1/sqrt(2048)
#define INV_SQRT_S 0.02209708691207961f

__device__ __forceinline__ void lds_barrier() {
    // LDS-only barrier: drain lgkmcnt but leave global prefetch loads (vmcnt) in flight.
    asm volatile("s_waitcnt lgkmcnt(0)\n\ts_barrier" ::: "memory");
}

__global__ __launch_bounds__(512, 2)
void fconv_ln(const float* __restrict__ x, const float* __restrict__ w,
              const float* __restrict__ gamma, const float* __restrict__ beta,
              float* __restrict__ out)
{
    const int h    = threadIdx.x;        // channel
    const int b    = blockIdx.x >> 4;    // 2048/128 = 16 tiles per batch
    const int tile = blockIdx.x & 15;
    const int s0   = tile * S_T;

    const float* xb = x   + ((size_t)b * S_LEN) * HDIM;
    float*       ob = out + ((size_t)b * S_LEN) * HDIM;

    // per-channel filter taps in registers
    float wr[KSZ];
#pragma unroll
    for (int k = 0; k < KSZ; ++k) wr[k] = w[k * HDIM + h];

    const float g  = gamma[h];
    const float be = beta[h];

    // sliding window: slot m holds x[(s0-64+m) mod S]; slot 0 is filled at j=0 before use
    float xw[KSZ];
#pragma unroll
    for (int m = 1; m < KSZ; ++m) {
        const int s = (s0 - KSZ + m + S_LEN) & (S_LEN - 1);
        xw[m] = xb[s * HDIM + h];
    }
    xw[0] = 0.0f;

    __shared__ float2 part[2][8];        // double-buffered per-wave partials
    const int lane = h & 63;
    const int wv   = h >> 6;

    // prefetch first row
    float xnext = xb[s0 * HDIM + h];

    for (int grp = 0; grp < S_T / KSZ; ++grp) {
        const int sbase = s0 + grp * KSZ;
#pragma unroll
        for (int j = 0; j < KSZ; ++j) {
            const int s = sbase + j;
            const float xcur = xnext;
            // prefetch next row (wrap harmlessly at tile end)
            {
                const int sn = (s + 1) & (S_LEN - 1);
                xnext = xb[sn * HDIM + h];
            }

            // conv over k=1..63 from the old window: 4 independent FMA chains
            float y0 = 0.f, y1 = 0.f, y2 = 0.f, y3 = 0.f;
#pragma unroll
            for (int k = 1; k < KSZ; k += 4) {
                y0 = fmaf(wr[k],     xw[(j - k)     & (KSZ - 1)], y0);
                y1 = fmaf(wr[k + 1], xw[(j - k - 1) & (KSZ - 1)], y1);
                y2 = fmaf(wr[k + 2], xw[(j - k - 2) & (KSZ - 1)], y2);
                if (k + 3 < KSZ)
                    y3 = fmaf(wr[k + 3], xw[(j - k - 3) & (KSZ - 1)], y3);
            }
            float y = (y0 + y1) + (y2 + y3);
            // h = x + (1/sqrt(S)) * (w0*x[s] + sum_{k>=1})
            const float hval = fmaf(INV_SQRT_S, fmaf(wr[0], xcur, y), xcur);

            // insert current row into window (slot j, statically indexed)
            xw[j & (KSZ - 1)] = xcur;

            // ---- LayerNorm across the 512 channels of this row ----
            float sum = hval;
            float sq  = hval * hval;
#pragma unroll
            for (int m = 1; m < 64; m <<= 1) {
                sum += __shfl_xor(sum, m, 64);
                sq  += __shfl_xor(sq,  m, 64);
            }
            const int pb = j & 1;
            if (lane == 0) part[pb][wv] = make_float2(sum, sq);
            lds_barrier();
            float ts = 0.f, tq = 0.f;
#pragma unroll
            for (int u = 0; u < 8; ++u) {
                const float2 p = part[pb][u];
                ts += p.x; tq += p.y;
            }
            const float mean = ts * (1.0f / 512.0f);
            const float var  = fmaf(tq, 1.0f / 512.0f, -mean * mean);
            const float rstd = rsqrtf(var + 1e-12f);
            ob[s * HDIM + h] = fmaf((hval - mean) * rstd, g, be);
        }
    }
}

extern "C" void kernel_launch(void* const* d_in, const int* in_sizes, int n_in,
                              void* d_out, int out_size, void* d_ws, size_t ws_size,
                              hipStream_t stream) {
    const float* x  = (const float*)d_in[0];   // [32, 2048, 512] fp32
    const float* w  = (const float*)d_in[1];   // [1, 64, 512]   fp32
    const float* g  = (const float*)d_in[2];   // [512]
    const float* b  = (const float*)d_in[3];   // [512]
    float* o        = (float*)d_out;           // [32, 2048, 512] fp32

    (void)in_sizes; (void)n_in; (void)out_size; (void)d_ws; (void)ws_size;
    fconv_ln<<<dim3(32 * (S_LEN / S_T)), dim3(HDIM), 0, stream>>>(x, w, g, b, o);
}

// Round 2
// 267.080 us; speedup vs baseline: 4.5853x; 4.5853x over previous
//
#include <hip/hip_runtime.h>

#define S_LEN 2048
#define HDIM  512
#define KSZ   64
#define S_T   128     // seq rows per block
#define PH    16      // rows per phase
// 1/sqrt(2048)
#define INV_SQRT_S 0.02209708691207961f

struct Smem {
    float  lh[PH][HDIM];     // 32 KB: h-values of current 16-row phase
    float2 part[PH][33];     // stage-1 partials (+1 pad col for stage-2 bank spread)
    float2 stats[PH];        // (mean, rstd) per row
};

__device__ __forceinline__ void lds_barrier() {
    // LDS-only barrier: drain lgkmcnt but leave global loads/stores (vmcnt) in flight.
    asm volatile("s_waitcnt lgkmcnt(0)\n\ts_barrier" ::: "memory");
}

// One 16-row conv phase. OFF = ring offset (0/16/32/48) as a template constant so
// every xw[] index is compile-time static -> arrays stay in VGPRs.
template <int OFF>
__device__ __forceinline__ void conv_phase(const float* __restrict__ xb, int sbase, int h,
                                           const float (&wr)[KSZ], float (&xw)[KSZ],
                                           float (&xp)[PH], float (&hv)[PH], Smem* sm)
{
#pragma unroll
    for (int j = 0; j < PH; ++j) {
        const float xcur = xp[j];
        // re-issue this prefetch slot for row (sbase + j + 16); wrap harmless
        xp[j] = xb[((sbase + j + PH) & (S_LEN - 1)) * HDIM + h];

        float y0 = 0.f, y1 = 0.f, y2 = 0.f, y3 = 0.f;
#pragma unroll
        for (int k = 1; k <= KSZ - 7; k += 4) {   // k = 1,5,...,57  covers taps 1..60
            y0 = fmaf(wr[k],     xw[(OFF + j - k)     & 63], y0);
            y1 = fmaf(wr[k + 1], xw[(OFF + j - k - 1) & 63], y1);
            y2 = fmaf(wr[k + 2], xw[(OFF + j - k - 2) & 63], y2);
            y3 = fmaf(wr[k + 3], xw[(OFF + j - k - 3) & 63], y3);
        }
        y0 = fmaf(wr[61], xw[(OFF + j - 61) & 63], y0);
        y1 = fmaf(wr[62], xw[(OFF + j - 62) & 63], y1);
        y2 = fmaf(wr[63], xw[(OFF + j - 63) & 63], y2);

        const float hval = fmaf(INV_SQRT_S, fmaf(wr[0], xcur, (y0 + y1) + (y2 + y3)), xcur);
        xw[(OFF + j) & 63] = xcur;   // insert current row, retire x[s-64]
        hv[j] = hval;
        sm->lh[j][h] = hval;         // stage for the LN reduction
    }
}

__device__ __forceinline__ void ln_phase(int sbase, int h, const float (&hv)[PH],
                                         float gm, float bt, float* __restrict__ ob, Smem* sm)
{
    lds_barrier();   // all lh writes visible

    // Stage 1: 32 threads per row, strided conflict-free reads
    const int r = h >> 5, c = h & 31;
    float s1 = 0.f, q1 = 0.f;
#pragma unroll
    for (int m = 0; m < 16; ++m) {
        const float v = sm->lh[r][c + (m << 5)];
        s1 += v;
        q1 = fmaf(v, v, q1);
    }
    sm->part[r][c] = make_float2(s1, q1);
    lds_barrier();

    // Stage 2: wave 0 only, 4 lanes per row
    if (h < 64) {
        const int rr = h >> 2, q = h & 3;
        float ts = 0.f, tq = 0.f;
#pragma unroll
        for (int i = 0; i < 8; ++i) {
            const float2 p = sm->part[rr][q * 8 + i];
            ts += p.x; tq += p.y;
        }
        ts += __shfl_xor(ts, 1, 64); tq += __shfl_xor(tq, 1, 64);
        ts += __shfl_xor(ts, 2, 64); tq += __shfl_xor(tq, 2, 64);
        if (q == 0) {
            const float mean = ts * (1.0f / 512.0f);
            const float var  = fmaf(tq, 1.0f / 512.0f, -mean * mean);
            sm->stats[rr] = make_float2(mean, rsqrtf(var + 1e-12f));
        }
    }
    lds_barrier();

    // Epilogue: normalize from registers, broadcast stats reads, coalesced stores
#pragma unroll
    for (int j = 0; j < PH; ++j) {
        const float2 st = sm->stats[j];
        ob[(sbase + j) * HDIM + h] = fmaf((hv[j] - st.x) * st.y, gm, bt);
    }
}

__global__ __launch_bounds__(512, 2)
void fconv_ln(const float* __restrict__ x, const float* __restrict__ w,
              const float* __restrict__ gamma, const float* __restrict__ beta,
              float* __restrict__ out)
{
    __shared__ Smem sm;
    const int h  = threadIdx.x;          // channel
    const int b  = blockIdx.x >> 4;      // 16 tiles of 128 rows per batch
    const int s0 = (blockIdx.x & 15) * S_T;

    const float* xb = x   + (size_t)b * S_LEN * HDIM;
    float*       ob = out + (size_t)b * S_LEN * HDIM;

    float wr[KSZ];
#pragma unroll
    for (int k = 0; k < KSZ; ++k) wr[k] = w[k * HDIM + h];
    const float gm = gamma[h], bt = beta[h];

    // window init: slot (s - s0) & 63 holds x[s] for s in [s0-63, s0-1]; slot 0 unused until insert
    float xw[KSZ];
#pragma unroll
    for (int d = 1; d < KSZ; ++d)
        xw[KSZ - d] = xb[((s0 - d) & (S_LEN - 1)) * HDIM + h];
    xw[0] = 0.f;

    // prefetch pipeline: rows s0 .. s0+15
    float xp[PH], hv[PH];
#pragma unroll
    for (int j = 0; j < PH; ++j) xp[j] = xb[(s0 + j) * HDIM + h];

    for (int grp = 0; grp < S_T / 64; ++grp) {   // 2 iterations
        const int base = s0 + grp * 64;
        conv_phase<0 >(xb, base +  0, h, wr, xw, xp, hv, &sm); ln_phase(base +  0, h, hv, gm, bt, ob, &sm);
        conv_phase<16>(xb, base + 16, h, wr, xw, xp, hv, &sm); ln_phase(base + 16, h, hv, gm, bt, ob, &sm);
        conv_phase<32>(xb, base + 32, h, wr, xw, xp, hv, &sm); ln_phase(base + 32, h, hv, gm, bt, ob, &sm);
        conv_phase<48>(xb, base + 48, h, wr, xw, xp, hv, &sm); ln_phase(base + 48, h, hv, gm, bt, ob, &sm);
    }
}

extern "C" void kernel_launch(void* const* d_in, const int* in_sizes, int n_in,
                              void* d_out, int out_size, void* d_ws, size_t ws_size,
                              hipStream_t stream) {
    const float* x  = (const float*)d_in[0];   // [32, 2048, 512] fp32
    const float* w  = (const float*)d_in[1];   // [1, 64, 512]   fp32
    const float* g  = (const float*)d_in[2];   // [512]
    const float* b  = (const float*)d_in[3];   // [512]
    float* o        = (float*)d_out;           // [32, 2048, 512] fp32

    (void)in_sizes; (void)n_in; (void)out_size; (void)d_ws; (void)ws_size;
    fconv_ln<<<dim3(32 * (S_LEN / S_T)), dim3(HDIM), 0, stream>>>(x, w, g, b, o);
}